// Round 2
// baseline (288.101 us; speedup 1.0000x reference)
//
#include <hip/hip_runtime.h>

#define FEAT 512
#define F4   128          // float4 per row
#define NSEG 1024
#define CHUNK 128         // rows per block in the sum pass

// ---------------- Pass 0: segment boundaries ----------------
// starts[s] = first row index with seg_id >= s (seg ids are sorted).
__global__ void seg_bounds_kernel(const int* __restrict__ seg,
                                  int* __restrict__ starts, int total) {
    int i = blockIdx.x * blockDim.x + threadIdx.x;
    if (i >= total) return;
    int cur = seg[i];
    int prev = (i == 0) ? -1 : seg[i - 1];
    for (int s = prev + 1; s <= cur; ++s) starts[s] = i;
    if (i == total - 1) {
        for (int s = cur + 1; s <= NSEG; ++s) starts[s] = total;
    }
}

__global__ void inv_count_kernel(const int* __restrict__ starts,
                                 float* __restrict__ invcnt) {
    int s = blockIdx.x * blockDim.x + threadIdx.x;
    if (s < NSEG) {
        int c = starts[s + 1] - starts[s];
        invcnt[s] = 1.0f / (float)(c > 0 ? c : 1);
    }
}

// ---------------- Pass A: balanced partial sums ----------------
// Each block owns CHUNK contiguous rows; lane t owns float4 column t.
// Segments overlapping the chunk are found via starts[] (no per-row branch);
// partial sums flushed with atomicAdd (rare: ~1.5 flushes/block).
__global__ __launch_bounds__(128) void seg_partial_kernel(const float* __restrict__ batch,
                                                          const int* __restrict__ seg,
                                                          const int* __restrict__ starts,
                                                          float* __restrict__ sums,
                                                          int total) {
    const int tid = threadIdx.x;           // f4 column 0..127
    const int r0 = blockIdx.x * CHUNK;
    if (r0 >= total) return;
    const int r1 = min(r0 + CHUNK, total);

    const float4* b4 = (const float4*)batch;
    const int s0 = seg[r0];
    const int s1 = seg[r1 - 1];

    for (int s = s0; s <= s1; ++s) {
        const int a = max(starts[s], r0);
        const int b = min(starts[s + 1], r1);
        if (a >= b) continue;              // empty segment in range
        float4 acc = make_float4(0.f, 0.f, 0.f, 0.f);
        for (int r = a; r < b; ++r) {
            float4 v = b4[(size_t)r * F4 + tid];
            acc.x += v.x; acc.y += v.y; acc.z += v.z; acc.w += v.w;
        }
        float* dst = sums + (size_t)s * FEAT + tid * 4;
        atomicAdd(dst + 0, acc.x);
        atomicAdd(dst + 1, acc.y);
        atomicAdd(dst + 2, acc.z);
        atomicAdd(dst + 3, acc.w);
    }
}

// ---------------- Pass B: balanced broadcast ----------------
// Grid-stride over output float4s: pure streaming write; sums/invcnt/seg
// reads are L2-hot (2 MB reused ~256x).
__global__ __launch_bounds__(256) void broadcast_kernel(const int* __restrict__ seg,
                                                        const float* __restrict__ sums,
                                                        const float* __restrict__ invcnt,
                                                        float* __restrict__ out,
                                                        int total) {
    const float4* s4 = (const float4*)sums;
    float4* o4 = (float4*)out;
    const size_t nf4 = (size_t)total * F4;
    const size_t stride = (size_t)gridDim.x * blockDim.x;
    for (size_t idx = (size_t)blockIdx.x * blockDim.x + threadIdx.x;
         idx < nf4; idx += stride) {
        const int row = (int)(idx >> 7);
        const int col = (int)(idx & 127);
        const int s   = seg[row];
        const float ic = invcnt[s];
        float4 m = s4[(size_t)s * F4 + col];
        m.x *= ic; m.y *= ic; m.z *= ic; m.w *= ic;
        o4[idx] = m;
    }
}

// ---------------- Fallback (round-1 fused kernel, needs only 4KB ws) ----------------
__global__ __launch_bounds__(512) void seg_mean_fused_kernel(const float* __restrict__ batch,
                                                             const int* __restrict__ starts,
                                                             float* __restrict__ out) {
    const int s      = blockIdx.x;
    const int tid    = threadIdx.x;
    const int lane_f = tid & (F4 - 1);
    const int rgrp   = tid >> 7;

    const int start = starts[s];
    const int end   = starts[s + 1];
    const int count = end - start;

    const float4* b4 = (const float4*)batch;
    float4 acc = make_float4(0.f, 0.f, 0.f, 0.f);
    for (int r = start + rgrp; r < end; r += 4) {
        float4 v = b4[(size_t)r * F4 + lane_f];
        acc.x += v.x; acc.y += v.y; acc.z += v.z; acc.w += v.w;
    }

    __shared__ float4 red[4][F4];
    red[rgrp][lane_f] = acc;
    __syncthreads();

    if (rgrp == 0) {
        float4 a = red[0][lane_f];
        float4 b = red[1][lane_f];
        float4 c = red[2][lane_f];
        float4 d = red[3][lane_f];
        const float inv = 1.0f / (float)(count > 0 ? count : 1);
        float4 m;
        m.x = (a.x + b.x + c.x + d.x) * inv;
        m.y = (a.y + b.y + c.y + d.y) * inv;
        m.z = (a.z + b.z + c.z + d.z) * inv;
        m.w = (a.w + b.w + c.w + d.w) * inv;
        red[0][lane_f] = m;
    }
    __syncthreads();

    const float4 mean = red[0][lane_f];
    float4* o4 = (float4*)out;
    for (int r = start + rgrp; r < end; r += 4) {
        o4[(size_t)r * F4 + lane_f] = mean;
    }
}

extern "C" void kernel_launch(void* const* d_in, const int* in_sizes, int n_in,
                              void* d_out, int out_size, void* d_ws, size_t ws_size,
                              hipStream_t stream) {
    const float* batch = (const float*)d_in[0];
    const int*   seg   = (const int*)d_in[1];
    float*       out   = (float*)d_out;
    const int total    = in_sizes[1];

    // ws layout: [sums: 2MB][starts: (NSEG+1)*4 @ 2MB][invcnt: NSEG*4 @ 2MB+8K]
    const size_t sums_bytes   = (size_t)NSEG * FEAT * sizeof(float);
    const size_t starts_off   = sums_bytes;
    const size_t invcnt_off   = sums_bytes + 8192;
    const size_t need         = invcnt_off + NSEG * sizeof(float);

    if (ws_size >= need) {
        float* sums   = (float*)d_ws;
        int*   starts = (int*)((char*)d_ws + starts_off);
        float* invcnt = (float*)((char*)d_ws + invcnt_off);

        hipMemsetAsync(sums, 0, sums_bytes, stream);
        seg_bounds_kernel<<<(total + 255) / 256, 256, 0, stream>>>(seg, starts, total);
        inv_count_kernel<<<NSEG / 256, 256, 0, stream>>>(starts, invcnt);

        const int nchunks = (total + CHUNK - 1) / CHUNK;
        seg_partial_kernel<<<nchunks, 128, 0, stream>>>(batch, seg, starts, sums, total);
        broadcast_kernel<<<2048, 256, 0, stream>>>(seg, sums, invcnt, out, total);
    } else {
        int* starts = (int*)d_ws;
        seg_bounds_kernel<<<(total + 255) / 256, 256, 0, stream>>>(seg, starts, total);
        seg_mean_fused_kernel<<<NSEG, 512, 0, stream>>>(batch, starts, out);
    }
}

// Round 3
// 283.263 us; speedup vs baseline: 1.0171x; 1.0171x over previous
//
#include <hip/hip_runtime.h>

#define FEAT 512
#define F4   128          // float4 per row
#define NSEG 1024

// ---------------- Pass 0: segment boundaries ----------------
// starts[s] = first row index with seg_id >= s (seg ids are sorted).
__global__ void seg_bounds_kernel(const int* __restrict__ seg,
                                  int* __restrict__ starts, int total) {
    int i = blockIdx.x * blockDim.x + threadIdx.x;
    if (i >= total) return;
    int cur = seg[i];
    int prev = (i == 0) ? -1 : seg[i - 1];
    for (int s = prev + 1; s <= cur; ++s) starts[s] = i;
    if (i == total - 1) {
        for (int s = cur + 1; s <= NSEG; ++s) starts[s] = total;
    }
}

// ---------------- Pass A: per-segment mean (read 512MB, write 2MB) ----------------
// One block per segment; 512 threads = 4 row-groups x 128 float4-columns.
// No atomics, no zero-init: each block exclusively owns means[s].
__global__ __launch_bounds__(512) void seg_mean_kernel(const float* __restrict__ batch,
                                                       const int* __restrict__ starts,
                                                       float* __restrict__ means) {
    const int s      = blockIdx.x;
    const int tid    = threadIdx.x;
    const int lane_f = tid & (F4 - 1);   // float4 column 0..127
    const int rgrp   = tid >> 7;         // row-group 0..3

    const int start = starts[s];
    const int end   = starts[s + 1];
    const int count = end - start;

    const float4* b4 = (const float4*)batch;
    float4 acc = make_float4(0.f, 0.f, 0.f, 0.f);
    for (int r = start + rgrp; r < end; r += 4) {
        float4 v = b4[(size_t)r * F4 + lane_f];
        acc.x += v.x; acc.y += v.y; acc.z += v.z; acc.w += v.w;
    }

    __shared__ float4 red[4][F4];
    red[rgrp][lane_f] = acc;
    __syncthreads();

    if (rgrp == 0) {
        float4 a = red[0][lane_f];
        float4 b = red[1][lane_f];
        float4 c = red[2][lane_f];
        float4 d = red[3][lane_f];
        const float inv = 1.0f / (float)(count > 0 ? count : 1);
        float4 m;
        m.x = (a.x + b.x + c.x + d.x) * inv;
        m.y = (a.y + b.y + c.y + d.y) * inv;
        m.z = (a.z + b.z + c.z + d.z) * inv;
        m.w = (a.w + b.w + c.w + d.w) * inv;
        ((float4*)means)[(size_t)s * F4 + lane_f] = m;
    }
}

// ---------------- Pass B: balanced broadcast (write 512MB) ----------------
// Grid-stride over output float4s; means (2MB) + seg (1MB) are L2-hot.
__global__ __launch_bounds__(256) void broadcast_kernel(const int* __restrict__ seg,
                                                        const float* __restrict__ means,
                                                        float* __restrict__ out,
                                                        int total) {
    const float4* m4 = (const float4*)means;
    float4* o4 = (float4*)out;
    const size_t nf4 = (size_t)total * F4;
    const size_t stride = (size_t)gridDim.x * blockDim.x;
    for (size_t idx = (size_t)blockIdx.x * blockDim.x + threadIdx.x;
         idx < nf4; idx += stride) {
        const int row = (int)(idx >> 7);
        const int col = (int)(idx & 127);
        const int s   = seg[row];
        o4[idx] = m4[(size_t)s * F4 + col];
    }
}

// ---------------- Fallback (round-1 fused kernel, needs only ~4KB ws) ----------------
__global__ __launch_bounds__(512) void seg_mean_fused_kernel(const float* __restrict__ batch,
                                                             const int* __restrict__ starts,
                                                             float* __restrict__ out) {
    const int s      = blockIdx.x;
    const int tid    = threadIdx.x;
    const int lane_f = tid & (F4 - 1);
    const int rgrp   = tid >> 7;

    const int start = starts[s];
    const int end   = starts[s + 1];
    const int count = end - start;

    const float4* b4 = (const float4*)batch;
    float4 acc = make_float4(0.f, 0.f, 0.f, 0.f);
    for (int r = start + rgrp; r < end; r += 4) {
        float4 v = b4[(size_t)r * F4 + lane_f];
        acc.x += v.x; acc.y += v.y; acc.z += v.z; acc.w += v.w;
    }

    __shared__ float4 red[4][F4];
    red[rgrp][lane_f] = acc;
    __syncthreads();

    if (rgrp == 0) {
        float4 a = red[0][lane_f];
        float4 b = red[1][lane_f];
        float4 c = red[2][lane_f];
        float4 d = red[3][lane_f];
        const float inv = 1.0f / (float)(count > 0 ? count : 1);
        float4 m;
        m.x = (a.x + b.x + c.x + d.x) * inv;
        m.y = (a.y + b.y + c.y + d.y) * inv;
        m.z = (a.z + b.z + c.z + d.z) * inv;
        m.w = (a.w + b.w + c.w + d.w) * inv;
        red[0][lane_f] = m;
    }
    __syncthreads();

    const float4 mean = red[0][lane_f];
    float4* o4 = (float4*)out;
    for (int r = start + rgrp; r < end; r += 4) {
        o4[(size_t)r * F4 + lane_f] = mean;
    }
}

extern "C" void kernel_launch(void* const* d_in, const int* in_sizes, int n_in,
                              void* d_out, int out_size, void* d_ws, size_t ws_size,
                              hipStream_t stream) {
    const float* batch = (const float*)d_in[0];
    const int*   seg   = (const int*)d_in[1];
    float*       out   = (float*)d_out;
    const int total    = in_sizes[1];

    // ws layout: [means: 2MB][starts: (NSEG+1)*4]
    const size_t means_bytes = (size_t)NSEG * FEAT * sizeof(float);
    const size_t starts_off  = means_bytes;
    const size_t need        = starts_off + (NSEG + 1) * sizeof(int);

    if (ws_size >= need) {
        float* means  = (float*)d_ws;
        int*   starts = (int*)((char*)d_ws + starts_off);

        seg_bounds_kernel<<<(total + 255) / 256, 256, 0, stream>>>(seg, starts, total);
        seg_mean_kernel<<<NSEG, 512, 0, stream>>>(batch, starts, means);
        broadcast_kernel<<<2048, 256, 0, stream>>>(seg, means, out, total);
    } else {
        int* starts = (int*)d_ws;
        seg_bounds_kernel<<<(total + 255) / 256, 256, 0, stream>>>(seg, starts, total);
        seg_mean_fused_kernel<<<NSEG, 512, 0, stream>>>(batch, starts, out);
    }
}

// Round 5
// 210.034 us; speedup vs baseline: 1.3717x; 1.3487x over previous
//
#include <hip/hip_runtime.h>

#define FEAT 512
#define F4   128          // float4 per row
#define NSEG 1024

typedef float f4_t __attribute__((ext_vector_type(4)));  // native vector: OK for nontemporal builtins

// ---------------- Pass 0: segment boundaries ----------------
// starts[s] = first row index with seg_id >= s (seg ids are sorted).
__global__ void seg_bounds_kernel(const int* __restrict__ seg,
                                  int* __restrict__ starts, int total) {
    int i = blockIdx.x * blockDim.x + threadIdx.x;
    if (i >= total) return;
    int cur = seg[i];
    int prev = (i == 0) ? -1 : seg[i - 1];
    for (int s = prev + 1; s <= cur; ++s) starts[s] = i;
    if (i == total - 1) {
        for (int s = cur + 1; s <= NSEG; ++s) starts[s] = total;
    }
}

// ---------------- Fused: one block per segment ----------------
// 512 threads = 4 row-groups x 128 float4-columns. Read loop unrolled x8
// (8 independent nontemporal loads in flight); LDS cross-group reduce;
// write loop unrolled x8 with mean held in registers (no loads at all).
__global__ __launch_bounds__(512) void seg_mean_fused_kernel(
        const float* __restrict__ batch,
        const int* __restrict__ starts,
        float* __restrict__ out) {
    const int s      = blockIdx.x;
    const int tid    = threadIdx.x;
    const int lane_f = tid & (F4 - 1);   // float4 column 0..127
    const int rgrp   = tid >> 7;         // row-group 0..3

    const int start = starts[s];
    const int end   = starts[s + 1];
    const int count = end - start;

    const f4_t* b4 = (const f4_t*)batch;

    f4_t a0 = (f4_t)(0.f);
    f4_t a1 = (f4_t)(0.f);

    int r = start + rgrp;
    // Unrolled x8: rows r, r+4, ..., r+28 (stride 4 = row-group interleave).
    for (; r + 28 < end; r += 32) {
        const f4_t* p = b4 + (size_t)r * F4 + lane_f;
        f4_t v0 = __builtin_nontemporal_load(p + 0 * 4 * F4);
        f4_t v1 = __builtin_nontemporal_load(p + 1 * 4 * F4);
        f4_t v2 = __builtin_nontemporal_load(p + 2 * 4 * F4);
        f4_t v3 = __builtin_nontemporal_load(p + 3 * 4 * F4);
        f4_t v4 = __builtin_nontemporal_load(p + 4 * 4 * F4);
        f4_t v5 = __builtin_nontemporal_load(p + 5 * 4 * F4);
        f4_t v6 = __builtin_nontemporal_load(p + 6 * 4 * F4);
        f4_t v7 = __builtin_nontemporal_load(p + 7 * 4 * F4);
        a0 += v0; a1 += v1;
        a0 += v2; a1 += v3;
        a0 += v4; a1 += v5;
        a0 += v6; a1 += v7;
    }
    for (; r < end; r += 4) {
        a0 += __builtin_nontemporal_load(b4 + (size_t)r * F4 + lane_f);
    }
    a0 += a1;

    __shared__ f4_t red[4][F4];
    red[rgrp][lane_f] = a0;
    __syncthreads();

    if (rgrp == 0) {
        f4_t p0 = red[0][lane_f];
        f4_t p1 = red[1][lane_f];
        f4_t p2 = red[2][lane_f];
        f4_t p3 = red[3][lane_f];
        const float inv = 1.0f / (float)(count > 0 ? count : 1);
        red[0][lane_f] = (p0 + p1 + p2 + p3) * inv;
    }
    __syncthreads();

    const f4_t mean = red[0][lane_f];
    f4_t* o4 = (f4_t*)out;

    r = start + rgrp;
    for (; r + 28 < end; r += 32) {
        f4_t* q = o4 + (size_t)r * F4 + lane_f;
        __builtin_nontemporal_store(mean, q + 0 * 4 * F4);
        __builtin_nontemporal_store(mean, q + 1 * 4 * F4);
        __builtin_nontemporal_store(mean, q + 2 * 4 * F4);
        __builtin_nontemporal_store(mean, q + 3 * 4 * F4);
        __builtin_nontemporal_store(mean, q + 4 * 4 * F4);
        __builtin_nontemporal_store(mean, q + 5 * 4 * F4);
        __builtin_nontemporal_store(mean, q + 6 * 4 * F4);
        __builtin_nontemporal_store(mean, q + 7 * 4 * F4);
    }
    for (; r < end; r += 4) {
        __builtin_nontemporal_store(mean, o4 + (size_t)r * F4 + lane_f);
    }
}

extern "C" void kernel_launch(void* const* d_in, const int* in_sizes, int n_in,
                              void* d_out, int out_size, void* d_ws, size_t ws_size,
                              hipStream_t stream) {
    const float* batch = (const float*)d_in[0];
    const int*   seg   = (const int*)d_in[1];
    float*       out   = (float*)d_out;
    const int total    = in_sizes[1];

    int* starts = (int*)d_ws;   // (NSEG+1) ints

    seg_bounds_kernel<<<(total + 255) / 256, 256, 0, stream>>>(seg, starts, total);
    seg_mean_fused_kernel<<<NSEG, 512, 0, stream>>>(batch, starts, out);
}

// Round 6
// 198.718 us; speedup vs baseline: 1.4498x; 1.0569x over previous
//
#include <hip/hip_runtime.h>

#define FEAT 512
#define F4   128          // float4 per row
#define NSEG 1024

typedef float f4_t __attribute__((ext_vector_type(4)));

// ---------------- Pass 0: segment boundaries ----------------
// starts[s] = first row index with seg_id >= s (seg ids are sorted).
__global__ void seg_bounds_kernel(const int* __restrict__ seg,
                                  int* __restrict__ starts, int total) {
    int i = blockIdx.x * blockDim.x + threadIdx.x;
    if (i >= total) return;
    int cur = seg[i];
    int prev = (i == 0) ? -1 : seg[i - 1];
    for (int s = prev + 1; s <= cur; ++s) starts[s] = i;
    if (i == total - 1) {
        for (int s = cur + 1; s <= NSEG; ++s) starts[s] = total;
    }
}

// ---------------- Pass A: per-segment mean -> scratch (read 512MB, write 2MB) ----------
// One block per segment; 512 threads = 4 row-groups x 128 float4-columns.
// x8-unrolled nontemporal read loop for MLP.
__global__ __launch_bounds__(512) void seg_mean_kernel(
        const float* __restrict__ batch,
        const int* __restrict__ starts,
        float* __restrict__ means) {
    const int s      = blockIdx.x;
    const int tid    = threadIdx.x;
    const int lane_f = tid & (F4 - 1);
    const int rgrp   = tid >> 7;

    const int start = starts[s];
    const int end   = starts[s + 1];
    const int count = end - start;

    const f4_t* b4 = (const f4_t*)batch;
    f4_t a0 = (f4_t)(0.f);
    f4_t a1 = (f4_t)(0.f);

    int r = start + rgrp;
    for (; r + 28 < end; r += 32) {
        const f4_t* p = b4 + (size_t)r * F4 + lane_f;
        f4_t v0 = __builtin_nontemporal_load(p + 0 * 4 * F4);
        f4_t v1 = __builtin_nontemporal_load(p + 1 * 4 * F4);
        f4_t v2 = __builtin_nontemporal_load(p + 2 * 4 * F4);
        f4_t v3 = __builtin_nontemporal_load(p + 3 * 4 * F4);
        f4_t v4 = __builtin_nontemporal_load(p + 4 * 4 * F4);
        f4_t v5 = __builtin_nontemporal_load(p + 5 * 4 * F4);
        f4_t v6 = __builtin_nontemporal_load(p + 6 * 4 * F4);
        f4_t v7 = __builtin_nontemporal_load(p + 7 * 4 * F4);
        a0 += v0; a1 += v1;
        a0 += v2; a1 += v3;
        a0 += v4; a1 += v5;
        a0 += v6; a1 += v7;
    }
    for (; r < end; r += 4) {
        a0 += __builtin_nontemporal_load(b4 + (size_t)r * F4 + lane_f);
    }
    a0 += a1;

    __shared__ f4_t red[4][F4];
    red[rgrp][lane_f] = a0;
    __syncthreads();

    if (rgrp == 0) {
        f4_t p0 = red[0][lane_f];
        f4_t p1 = red[1][lane_f];
        f4_t p2 = red[2][lane_f];
        f4_t p3 = red[3][lane_f];
        const float inv = 1.0f / (float)(count > 0 ? count : 1);
        ((f4_t*)means)[(size_t)s * F4 + lane_f] = (p0 + p1 + p2 + p3) * inv;
    }
}

// ---------------- Pass B: chunk-balanced broadcast (write 512MB) ----------------
// Each block owns exactly 256 output rows -> zero load imbalance.
// The <=3 overlapping segment means are hoisted into a register (one dependent
// load per ~100 rows), then pure x8-unrolled NT streaming stores.
__global__ __launch_bounds__(256) void broadcast_chunk_kernel(
        const int* __restrict__ seg,
        const int* __restrict__ starts,
        const float* __restrict__ means,
        float* __restrict__ out, int total) {
    const int tid  = threadIdx.x;
    const int lane = tid & (F4 - 1);   // f4 column 0..127
    const int rg   = tid >> 7;         // row-group 0..1
    const int r0   = blockIdx.x * 256;
    if (r0 >= total) return;
    const int r1   = min(r0 + 256, total);

    const int s0 = seg[r0];
    const int s1 = seg[r1 - 1];

    const f4_t* m4 = (const f4_t*)means;
    f4_t* o4 = (f4_t*)out;

    for (int s = s0; s <= s1; ++s) {
        const int a = max(starts[s], r0);
        const int b = min(starts[s + 1], r1);
        if (a >= b) continue;          // empty segment
        const f4_t mean = m4[(size_t)s * F4 + lane];
        int r = a + rg;
        // rows r, r+2, ..., r+14 (stride 2 = row-group interleave), x8 unroll
        for (; r + 14 < b; r += 16) {
            f4_t* q = o4 + (size_t)r * F4 + lane;
            __builtin_nontemporal_store(mean, q + 0 * 2 * F4);
            __builtin_nontemporal_store(mean, q + 1 * 2 * F4);
            __builtin_nontemporal_store(mean, q + 2 * 2 * F4);
            __builtin_nontemporal_store(mean, q + 3 * 2 * F4);
            __builtin_nontemporal_store(mean, q + 4 * 2 * F4);
            __builtin_nontemporal_store(mean, q + 5 * 2 * F4);
            __builtin_nontemporal_store(mean, q + 6 * 2 * F4);
            __builtin_nontemporal_store(mean, q + 7 * 2 * F4);
        }
        for (; r < b; r += 2) {
            __builtin_nontemporal_store(mean, o4 + (size_t)r * F4 + lane);
        }
    }
}

// ---------------- Fallback: round-5 fused kernel (needs only ~4KB ws) ----------------
__global__ __launch_bounds__(512) void seg_mean_fused_kernel(
        const float* __restrict__ batch,
        const int* __restrict__ starts,
        float* __restrict__ out) {
    const int s      = blockIdx.x;
    const int tid    = threadIdx.x;
    const int lane_f = tid & (F4 - 1);
    const int rgrp   = tid >> 7;

    const int start = starts[s];
    const int end   = starts[s + 1];
    const int count = end - start;

    const f4_t* b4 = (const f4_t*)batch;
    f4_t a0 = (f4_t)(0.f);
    f4_t a1 = (f4_t)(0.f);

    int r = start + rgrp;
    for (; r + 28 < end; r += 32) {
        const f4_t* p = b4 + (size_t)r * F4 + lane_f;
        f4_t v0 = __builtin_nontemporal_load(p + 0 * 4 * F4);
        f4_t v1 = __builtin_nontemporal_load(p + 1 * 4 * F4);
        f4_t v2 = __builtin_nontemporal_load(p + 2 * 4 * F4);
        f4_t v3 = __builtin_nontemporal_load(p + 3 * 4 * F4);
        f4_t v4 = __builtin_nontemporal_load(p + 4 * 4 * F4);
        f4_t v5 = __builtin_nontemporal_load(p + 5 * 4 * F4);
        f4_t v6 = __builtin_nontemporal_load(p + 6 * 4 * F4);
        f4_t v7 = __builtin_nontemporal_load(p + 7 * 4 * F4);
        a0 += v0; a1 += v1;
        a0 += v2; a1 += v3;
        a0 += v4; a1 += v5;
        a0 += v6; a1 += v7;
    }
    for (; r < end; r += 4) {
        a0 += __builtin_nontemporal_load(b4 + (size_t)r * F4 + lane_f);
    }
    a0 += a1;

    __shared__ f4_t red[4][F4];
    red[rgrp][lane_f] = a0;
    __syncthreads();

    if (rgrp == 0) {
        f4_t p0 = red[0][lane_f];
        f4_t p1 = red[1][lane_f];
        f4_t p2 = red[2][lane_f];
        f4_t p3 = red[3][lane_f];
        const float inv = 1.0f / (float)(count > 0 ? count : 1);
        red[0][lane_f] = (p0 + p1 + p2 + p3) * inv;
    }
    __syncthreads();

    const f4_t mean = red[0][lane_f];
    f4_t* o4 = (f4_t*)out;

    r = start + rgrp;
    for (; r + 28 < end; r += 32) {
        f4_t* q = o4 + (size_t)r * F4 + lane_f;
        __builtin_nontemporal_store(mean, q + 0 * 4 * F4);
        __builtin_nontemporal_store(mean, q + 1 * 4 * F4);
        __builtin_nontemporal_store(mean, q + 2 * 4 * F4);
        __builtin_nontemporal_store(mean, q + 3 * 4 * F4);
        __builtin_nontemporal_store(mean, q + 4 * 4 * F4);
        __builtin_nontemporal_store(mean, q + 5 * 4 * F4);
        __builtin_nontemporal_store(mean, q + 6 * 4 * F4);
        __builtin_nontemporal_store(mean, q + 7 * 4 * F4);
    }
    for (; r < end; r += 4) {
        __builtin_nontemporal_store(mean, o4 + (size_t)r * F4 + lane_f);
    }
}

extern "C" void kernel_launch(void* const* d_in, const int* in_sizes, int n_in,
                              void* d_out, int out_size, void* d_ws, size_t ws_size,
                              hipStream_t stream) {
    const float* batch = (const float*)d_in[0];
    const int*   seg   = (const int*)d_in[1];
    float*       out   = (float*)d_out;
    const int total    = in_sizes[1];

    // ws layout: [means: 2MB][starts: (NSEG+1)*4]
    const size_t means_bytes = (size_t)NSEG * FEAT * sizeof(float);
    const size_t need        = means_bytes + (NSEG + 1) * sizeof(int);

    if (ws_size >= need) {
        float* means  = (float*)d_ws;
        int*   starts = (int*)((char*)d_ws + means_bytes);

        seg_bounds_kernel<<<(total + 255) / 256, 256, 0, stream>>>(seg, starts, total);
        seg_mean_kernel<<<NSEG, 512, 0, stream>>>(batch, starts, means);
        const int nchunks = (total + 255) / 256;
        broadcast_chunk_kernel<<<nchunks, 256, 0, stream>>>(seg, starts, means, out, total);
    } else {
        int* starts = (int*)d_ws;
        seg_bounds_kernel<<<(total + 255) / 256, 256, 0, stream>>>(seg, starts, total);
        seg_mean_fused_kernel<<<NSEG, 512, 0, stream>>>(batch, starts, out);
    }
}

// Round 7
// 197.522 us; speedup vs baseline: 1.4586x; 1.0061x over previous
//
#include <hip/hip_runtime.h>

#define FEAT 512
#define F4   128          // float4 per row
#define NSEG 1024
#define CHUNK 256         // rows per block in sum/broadcast passes

typedef float f4_t __attribute__((ext_vector_type(4)));

// ---------------- K1: segment boundaries + zero sums ----------------
// starts[s] = first row index with seg_id >= s (seg ids sorted).
// Also zeroes the 2MB sums buffer (avoids rocclr fill node — round-2 lesson).
__global__ void bounds_zero_kernel(const int* __restrict__ seg,
                                   int* __restrict__ starts,
                                   float* __restrict__ sums, int total) {
    int i = blockIdx.x * blockDim.x + threadIdx.x;
    if (sums != nullptr && i < NSEG * FEAT / 2) {
        ((float2*)sums)[i] = make_float2(0.f, 0.f);
    }
    if (i >= total) return;
    int cur = seg[i];
    int prev = (i == 0) ? -1 : seg[i - 1];
    for (int s = prev + 1; s <= cur; ++s) starts[s] = i;
    if (i == total - 1) {
        for (int s = cur + 1; s <= NSEG; ++s) starts[s] = total;
    }
}

// ---------------- K2: chunk-balanced partial sums (read 512MB) ----------------
// Each block owns exactly CHUNK rows -> zero imbalance, 32 waves/CU.
// 512 threads = 4 row-groups x 128 f4-columns. Per overlapping segment
// (block-uniform bounds): x8-unrolled NT reads -> register acc -> LDS
// combine across row-groups -> rg0 flushes 4 scalar atomicAdds.
__global__ __launch_bounds__(512) void chunk_sum_kernel(
        const float* __restrict__ batch,
        const int* __restrict__ seg,
        const int* __restrict__ starts,
        float* __restrict__ sums, int total) {
    const int tid  = threadIdx.x;
    const int lane = tid & (F4 - 1);   // f4 column 0..127
    const int rg   = tid >> 7;         // row-group 0..3
    const int r0   = blockIdx.x * CHUNK;
    if (r0 >= total) return;
    const int r1   = min(r0 + CHUNK, total);

    const int s0 = seg[r0];
    const int s1 = seg[r1 - 1];

    const f4_t* b4 = (const f4_t*)batch;
    __shared__ f4_t red[4][F4];

    for (int s = s0; s <= s1; ++s) {
        const int a = max(starts[s], r0);      // block-uniform
        const int b = min(starts[s + 1], r1);  // block-uniform
        if (a >= b) continue;                  // uniform skip (empty segment)

        f4_t a0 = (f4_t)(0.f);
        f4_t a1 = (f4_t)(0.f);
        int r = a + rg;
        for (; r + 28 < b; r += 32) {
            const f4_t* p = b4 + (size_t)r * F4 + lane;
            f4_t v0 = __builtin_nontemporal_load(p + 0 * 4 * F4);
            f4_t v1 = __builtin_nontemporal_load(p + 1 * 4 * F4);
            f4_t v2 = __builtin_nontemporal_load(p + 2 * 4 * F4);
            f4_t v3 = __builtin_nontemporal_load(p + 3 * 4 * F4);
            f4_t v4 = __builtin_nontemporal_load(p + 4 * 4 * F4);
            f4_t v5 = __builtin_nontemporal_load(p + 5 * 4 * F4);
            f4_t v6 = __builtin_nontemporal_load(p + 6 * 4 * F4);
            f4_t v7 = __builtin_nontemporal_load(p + 7 * 4 * F4);
            a0 += v0; a1 += v1;
            a0 += v2; a1 += v3;
            a0 += v4; a1 += v5;
            a0 += v6; a1 += v7;
        }
        for (; r < b; r += 4) {
            a0 += __builtin_nontemporal_load(b4 + (size_t)r * F4 + lane);
        }
        a0 += a1;

        red[rg][lane] = a0;
        __syncthreads();
        if (rg == 0) {
            f4_t t = red[0][lane] + red[1][lane] + red[2][lane] + red[3][lane];
            float* dst = sums + (size_t)s * FEAT + lane * 4;
            atomicAdd(dst + 0, t.x);
            atomicAdd(dst + 1, t.y);
            atomicAdd(dst + 2, t.z);
            atomicAdd(dst + 3, t.w);
        }
        __syncthreads();
    }
}

// ---------------- K3: chunk-balanced broadcast (write 512MB) ----------------
// Each block owns exactly CHUNK output rows. Segment mean hoisted to a
// register (sums[s]/count), then pure x8-unrolled NT streaming stores.
__global__ __launch_bounds__(256) void broadcast_chunk_kernel(
        const int* __restrict__ seg,
        const int* __restrict__ starts,
        const float* __restrict__ sums,
        float* __restrict__ out, int total) {
    const int tid  = threadIdx.x;
    const int lane = tid & (F4 - 1);   // f4 column 0..127
    const int rg   = tid >> 7;         // row-group 0..1
    const int r0   = blockIdx.x * CHUNK;
    if (r0 >= total) return;
    const int r1   = min(r0 + CHUNK, total);

    const int s0 = seg[r0];
    const int s1 = seg[r1 - 1];

    const f4_t* m4 = (const f4_t*)sums;
    f4_t* o4 = (f4_t*)out;

    for (int s = s0; s <= s1; ++s) {
        const int sa = starts[s];
        const int sb = starts[s + 1];
        const int a = max(sa, r0);
        const int b = min(sb, r1);
        if (a >= b) continue;
        const int count = sb - sa;
        const float inv = 1.0f / (float)(count > 0 ? count : 1);
        const f4_t mean = m4[(size_t)s * F4 + lane] * inv;
        int r = a + rg;
        for (; r + 14 < b; r += 16) {
            f4_t* q = o4 + (size_t)r * F4 + lane;
            __builtin_nontemporal_store(mean, q + 0 * 2 * F4);
            __builtin_nontemporal_store(mean, q + 1 * 2 * F4);
            __builtin_nontemporal_store(mean, q + 2 * 2 * F4);
            __builtin_nontemporal_store(mean, q + 3 * 2 * F4);
            __builtin_nontemporal_store(mean, q + 4 * 2 * F4);
            __builtin_nontemporal_store(mean, q + 5 * 2 * F4);
            __builtin_nontemporal_store(mean, q + 6 * 2 * F4);
            __builtin_nontemporal_store(mean, q + 7 * 2 * F4);
        }
        for (; r < b; r += 2) {
            __builtin_nontemporal_store(mean, o4 + (size_t)r * F4 + lane);
        }
    }
}

// ---------------- Fallback: round-5 fused kernel (needs only ~4KB ws) ----------------
__global__ __launch_bounds__(512) void seg_mean_fused_kernel(
        const float* __restrict__ batch,
        const int* __restrict__ starts,
        float* __restrict__ out) {
    const int s      = blockIdx.x;
    const int tid    = threadIdx.x;
    const int lane_f = tid & (F4 - 1);
    const int rgrp   = tid >> 7;

    const int start = starts[s];
    const int end   = starts[s + 1];
    const int count = end - start;

    const f4_t* b4 = (const f4_t*)batch;
    f4_t a0 = (f4_t)(0.f);
    f4_t a1 = (f4_t)(0.f);

    int r = start + rgrp;
    for (; r + 28 < end; r += 32) {
        const f4_t* p = b4 + (size_t)r * F4 + lane_f;
        f4_t v0 = __builtin_nontemporal_load(p + 0 * 4 * F4);
        f4_t v1 = __builtin_nontemporal_load(p + 1 * 4 * F4);
        f4_t v2 = __builtin_nontemporal_load(p + 2 * 4 * F4);
        f4_t v3 = __builtin_nontemporal_load(p + 3 * 4 * F4);
        f4_t v4 = __builtin_nontemporal_load(p + 4 * 4 * F4);
        f4_t v5 = __builtin_nontemporal_load(p + 5 * 4 * F4);
        f4_t v6 = __builtin_nontemporal_load(p + 6 * 4 * F4);
        f4_t v7 = __builtin_nontemporal_load(p + 7 * 4 * F4);
        a0 += v0; a1 += v1;
        a0 += v2; a1 += v3;
        a0 += v4; a1 += v5;
        a0 += v6; a1 += v7;
    }
    for (; r < end; r += 4) {
        a0 += __builtin_nontemporal_load(b4 + (size_t)r * F4 + lane_f);
    }
    a0 += a1;

    __shared__ f4_t red[4][F4];
    red[rgrp][lane_f] = a0;
    __syncthreads();

    if (rgrp == 0) {
        f4_t p0 = red[0][lane_f];
        f4_t p1 = red[1][lane_f];
        f4_t p2 = red[2][lane_f];
        f4_t p3 = red[3][lane_f];
        const float inv = 1.0f / (float)(count > 0 ? count : 1);
        red[0][lane_f] = (p0 + p1 + p2 + p3) * inv;
    }
    __syncthreads();

    const f4_t mean = red[0][lane_f];
    f4_t* o4 = (f4_t*)out;

    r = start + rgrp;
    for (; r + 28 < end; r += 32) {
        f4_t* q = o4 + (size_t)r * F4 + lane_f;
        __builtin_nontemporal_store(mean, q + 0 * 4 * F4);
        __builtin_nontemporal_store(mean, q + 1 * 4 * F4);
        __builtin_nontemporal_store(mean, q + 2 * 4 * F4);
        __builtin_nontemporal_store(mean, q + 3 * 4 * F4);
        __builtin_nontemporal_store(mean, q + 4 * 4 * F4);
        __builtin_nontemporal_store(mean, q + 5 * 4 * F4);
        __builtin_nontemporal_store(mean, q + 6 * 4 * F4);
        __builtin_nontemporal_store(mean, q + 7 * 4 * F4);
    }
    for (; r < end; r += 4) {
        __builtin_nontemporal_store(mean, o4 + (size_t)r * F4 + lane_f);
    }
}

extern "C" void kernel_launch(void* const* d_in, const int* in_sizes, int n_in,
                              void* d_out, int out_size, void* d_ws, size_t ws_size,
                              hipStream_t stream) {
    const float* batch = (const float*)d_in[0];
    const int*   seg   = (const int*)d_in[1];
    float*       out   = (float*)d_out;
    const int total    = in_sizes[1];

    // ws layout: [sums: 2MB][starts: (NSEG+1)*4]
    const size_t sums_bytes = (size_t)NSEG * FEAT * sizeof(float);
    const size_t need       = sums_bytes + (NSEG + 1) * sizeof(int);

    const int nblk256 = (total + 255) / 256;

    if (ws_size >= need) {
        float* sums   = (float*)d_ws;
        int*   starts = (int*)((char*)d_ws + sums_bytes);

        bounds_zero_kernel<<<nblk256, 256, 0, stream>>>(seg, starts, sums, total);
        const int nchunks = (total + CHUNK - 1) / CHUNK;
        chunk_sum_kernel<<<nchunks, 512, 0, stream>>>(batch, seg, starts, sums, total);
        broadcast_chunk_kernel<<<nchunks, 256, 0, stream>>>(seg, starts, sums, out, total);
    } else {
        int* starts = (int*)d_ws;
        bounds_zero_kernel<<<nblk256, 256, 0, stream>>>(seg, starts, nullptr, total);
        seg_mean_fused_kernel<<<NSEG, 512, 0, stream>>>(batch, starts, out);
    }
}